// Round 3
// baseline (60.488 us; speedup 1.0000x reference)
//
#include <hip/hip_runtime.h>
#include <hip/hip_bf16.h>

// out[b][d][n] = E[n][d], b<32, d<128, n<16384.
// Strategy: (1) LDS-transpose E into out[0] (8 MB). (2) Linear broadcast-copy
// out[0] -> out[1..31] with long contiguous streams (fill-kernel shape):
// 128 KB contiguous per block, vector loads (cache-resident src) +
// nontemporal vector stores. Floor = 268 MB stores at ~7 TB/s ≈ 38 µs.

#define NN 16384
#define DD 128
#define NT 64
#define NBATCH 32

// native clang vector: __builtin_nontemporal_store requires this, not the
// HIP_vector_type class float4.
typedef float f4_t __attribute__((ext_vector_type(4)));

__global__ __launch_bounds__(256) void transpose_b0_kernel(
    const float* __restrict__ E, float* __restrict__ out) {
    __shared__ float lds[DD][NT + 1];  // pad +1: phase-2 reads 2-way (free)

    const int n0 = blockIdx.x * NT;
    const int tid = threadIdx.x;

    // Load E[n0..n0+63][:], coalesced f4 along d; transpose into LDS.
    {
        const int c = tid & 31;   // d = 4c..4c+3
        const int r = tid >> 5;   // n row 0..7 per iter group
        #pragma unroll
        for (int it = 0; it < NT / 8; ++it) {
            const int n = r + it * 8;
            const f4_t v = *reinterpret_cast<const f4_t*>(
                &E[(size_t)(n0 + n) * DD + (c << 2)]);
            lds[(c << 2) + 0][n] = v.x;
            lds[(c << 2) + 1][n] = v.y;
            lds[(c << 2) + 2][n] = v.z;
            lds[(c << 2) + 3][n] = v.w;
        }
    }
    __syncthreads();

    // Write out[0][d][n0..n0+63]: 128 rows x 16 f4 = 2048 f4.
    const int j = tid & 15;
    const int row0 = tid >> 4;
    #pragma unroll
    for (int it = 0; it < DD / 16; ++it) {  // 8 iters
        const int d = row0 + it * 16;
        f4_t v;
        v.x = lds[d][(j << 2) + 0];
        v.y = lds[d][(j << 2) + 1];
        v.z = lds[d][(j << 2) + 2];
        v.w = lds[d][(j << 2) + 3];
        *reinterpret_cast<f4_t*>(&out[(size_t)d * NN + n0 + (j << 2)]) = v;
    }
}

// Copy out[0] (8 MB) to out[b], b = 1..31. blockIdx.x = batch-1 (31),
// blockIdx.y = 128 KB chunk (64). Co-dispatched blocks share the same
// source chunk -> L2/L3 hits. Nontemporal stores keep src cache-resident.
__global__ __launch_bounds__(256) void bcast_kernel(
    const float* __restrict__ src, float* __restrict__ out) {
    const size_t BSZ = (size_t)DD * NN;      // 2,097,152 floats / batch
    const size_t CHUNK = BSZ / 64;           // 32,768 floats = 128 KB
    const size_t base = (size_t)blockIdx.y * CHUNK;
    const float* __restrict__ s = src + base;
    float* __restrict__ dst = out + (size_t)(blockIdx.x + 1) * BSZ + base;
    const int tid = threadIdx.x;

    #pragma unroll 8
    for (int it = 0; it < 32; ++it) {        // 32 * 256 * 16B = 128 KB
        const size_t idx = (size_t)(it * 256 + tid) << 2;
        const f4_t v = *reinterpret_cast<const f4_t*>(&s[idx]);
        __builtin_nontemporal_store(v, reinterpret_cast<f4_t*>(&dst[idx]));
    }
}

extern "C" void kernel_launch(void* const* d_in, const int* in_sizes, int n_in,
                              void* d_out, int out_size, void* d_ws, size_t ws_size,
                              hipStream_t stream) {
    const float* E = (const float*)d_in[0];  // [16384,128]
    float* out = (float*)d_out;              // [32,128,16384,1]

    hipLaunchKernelGGL(transpose_b0_kernel, dim3(NN / NT), dim3(256), 0, stream,
                       E, out);
    hipLaunchKernelGGL(bcast_kernel, dim3(NBATCH - 1, 64), dim3(256), 0, stream,
                       out, out);
}

// Round 4
// 55.626 us; speedup vs baseline: 1.0874x; 1.0874x over previous
//
#include <hip/hip_runtime.h>
#include <hip/hip_bf16.h>

// out[b][d][n] = E[n][d], b<32, d<128, n<16384.
// Single kernel, register broadcast: block = (d, 2048-n chunk). Each thread
// loads 8 strided E scalars ONCE (total E read = 8 MB, L3-resident), packs
// 2 float4, stores to all 32 batches. Every store instruction is a
// wave-contiguous 1 KB segment; per-batch runs are 8 KB contiguous.
// Floor: 268 MB stores at ~7 TB/s ~= 38 us.

#define NN 16384
#define DD 128
#define NB 32
#define CHUNK 2048  // n per block

typedef float f4_t __attribute__((ext_vector_type(4)));

__global__ __launch_bounds__(256) void tree_embed_bcast_kernel(
    const float* __restrict__ E, float* __restrict__ out) {
    const int d  = blockIdx.x;           // 0..127
    const int n0 = blockIdx.y * CHUNK;   // 0,2048,...,14336
    const int t  = threadIdx.x;          // 0..255

    // Thread t owns n = n0+4t..n0+4t+3 and n0+1024+4t..n0+1024+4t+3.
    // 8 scalar loads, stride 512 B (one E column) — L3-resident after warm.
    const float* e0 = E + (size_t)(n0 + (t << 2)) * DD + d;
    const float* e1 = e0 + (size_t)1024 * DD;
    f4_t va, vb;
    va.x = e0[0 * DD]; va.y = e0[1 * DD]; va.z = e0[2 * DD]; va.w = e0[3 * DD];
    vb.x = e1[0 * DD]; vb.y = e1[1 * DD]; vb.z = e1[2 * DD]; vb.w = e1[3 * DD];

    // Store to all 32 batches. Per store instr: lanes t=0..63 write
    // consecutive 16 B => 1 KB contiguous per wave.
    float* o = out + (size_t)d * NN + n0 + (t << 2);
    const size_t BSTRIDE = (size_t)DD * NN;  // 2,097,152 floats
    #pragma unroll
    for (int b = 0; b < NB; ++b) {
        float* p = o + (size_t)b * BSTRIDE;
        *reinterpret_cast<f4_t*>(p) = va;
        *reinterpret_cast<f4_t*>(p + 1024) = vb;
    }
}

extern "C" void kernel_launch(void* const* d_in, const int* in_sizes, int n_in,
                              void* d_out, int out_size, void* d_ws, size_t ws_size,
                              hipStream_t stream) {
    const float* E = (const float*)d_in[0];  // [16384,128]
    float* out = (float*)d_out;              // [32,128,16384,1]
    dim3 grid(DD, NN / CHUNK);               // 128 x 8 = 1024 blocks
    hipLaunchKernelGGL(tree_embed_bcast_kernel, grid, dim3(256), 0, stream,
                       E, out);
}